// Round 6
// baseline (271.289 us; speedup 1.0000x reference)
//
#include <hip/hip_runtime.h>
#include <math.h>

// HuberEMA: y[t] = y[t-1] + (1-a[c]) * clamp(x[t]-y[t-1], -d, +d); y[0] = x[0]
// B=32, T=2048, C=512 fp32. 16384 chains -> 256 blocks x 64 lanes (1 wave/CU).
// Roofline: 268 MB => ~43 us @ 6.3 TB/s.
//
// R4/R5 post-mortem: both ~110 us regardless of inner structure => shared
// bottleneck was bursty shallow prefetch (16 KB once per tile, drained by a
// full vmcnt wait at reg->LDS staging) -> ~2 B/cyc/CU read BW. Fix (T3/T4):
// global_load_lds DMA into a 4-slot LDS ring + counted vmcnt(N) waits that
// never drain to 0 in the main loop. 4 tiles x 8 KB = 32 KB/CU in flight
// continuously (~3.5x Little's-law need at ~900 cyc HBM latency).
//
// Per 32-t tile: s_waitcnt vmcnt(48) [exact FIFO count] -> 32 ds_read xin
// -> 32-step serial chain (y -> LDS scalar, conflict-free) -> repack: 8
// ds_read_b128 + 8 global dwordx4 stores -> issue 8 global_load_lds for
// tile k+4 into the slot just freed. Head waits 24/32/40; tail 48/40/32/24.
// Every asm waitcnt is followed by sched_barrier(0)  [guide rule #18].

#define TT   2048
#define CC   512
#define TILE 32
#define NTIL (TT / TILE)   // 64 tiles
#define LPT  8             // 1 KB global_load_lds ops per tile (8 KB tile)
#define RING 4             // ring depth; vmcnt count cap => 4 max

__device__ __forceinline__ void async16(const float* g, float* l) {
    // 64 lanes x 16 B: per-lane global src, wave-uniform LDS dst (+lane*16)
    __builtin_amdgcn_global_load_lds(
        (const __attribute__((address_space(1))) void*)g,
        (__attribute__((address_space(3))) void*)l, 16, 0, 0);
}

template<int N> __device__ __forceinline__ void vm_wait() {
    if constexpr (N == 24) asm volatile("s_waitcnt vmcnt(24)" ::: "memory");
    else if constexpr (N == 32) asm volatile("s_waitcnt vmcnt(32)" ::: "memory");
    else if constexpr (N == 40) asm volatile("s_waitcnt vmcnt(40)" ::: "memory");
    else if constexpr (N == 48) asm volatile("s_waitcnt vmcnt(48)" ::: "memory");
    else                        asm volatile("s_waitcnt vmcnt(0)"  ::: "memory");
    __builtin_amdgcn_sched_barrier(0);
}

template<int WAITN, bool PF>
__device__ __forceinline__ void tile_body(int k, const float* __restrict__ xl,
                                          float* __restrict__ yl,
                                          float* __restrict__ xslot,
                                          float* __restrict__ ysb,
                                          float& yv, float oma, float d, int lane)
{
    // 1) wait until THIS tile's 8 DMA loads landed (counted, never to 0)
    vm_wait<WAITN>();

    // 2) LDS -> regs: [t][ch] tile, lane reads its channel column
    //    (64 consecutive words/wave = 2-way bank alias = free)
    float xin[TILE];
    #pragma unroll
    for (int i = 0; i < TILE; ++i) xin[i] = xslot[i * 64 + lane];
    __builtin_amdgcn_sched_barrier(0);

    // 3) serial recurrence; y -> LDS scalar (conflict-free)
    #pragma unroll
    for (int i = 0; i < TILE; ++i) {
        float r = xin[i] - yv;
        yv += oma * fminf(fmaxf(r, -d), d);
        ysb[i * 64 + lane] = yv;
    }
    __builtin_amdgcn_sched_barrier(0);

    // 4) repack y: 8 ds_read_b128 (ysb offset g*1024 + lane*16, linear)
    //    + 8 coalesced global dwordx4 stores (1 KB/instruction)
    #pragma unroll
    for (int g = 0; g < LPT; ++g) {
        float4 v = *(const float4*)&ysb[g * 256 + (lane << 2)];
        *(float4*)(yl + (size_t)(k * TILE + g * 4) * CC) = v;
    }
    __builtin_amdgcn_sched_barrier(0);

    // 5) issue DMA for tile k+RING into the slot just consumed (xin reads
    //    retired before issue -> no overwrite hazard; arrival guarded by
    //    the counted vmcnt at tile k+RING)
    if (PF) {
        #pragma unroll
        for (int g = 0; g < LPT; ++g)
            async16(xl + (size_t)((k + RING) * TILE + g * 4) * CC,
                    &xslot[g * 256]);
    }
    __builtin_amdgcn_sched_barrier(0);
}

__global__ __launch_bounds__(64, 1)
void huber_ema_kernel(const float* __restrict__ x,
                      const float* __restrict__ logit_alpha,
                      const float* __restrict__ delta,
                      float* __restrict__ y)
{
    const int blk  = blockIdx.x;     // 0..255
    const int b    = blk >> 3;       // batch
    const int cc   = blk & 7;        // 64-wide channel chunk
    const int lane = threadIdx.x;    // 0..63

    __shared__ float xs[RING][TILE * 64];   // 4 x 8 KB ring
    __shared__ float ys[TILE * 64];         // 8 KB y repack buffer

    // per-chain alpha: a = clip(sigmoid(la), 1e-4, 1-1e-4); uniform delta.
    // These loads + yv init precede all DMA issues (oldest in vmcnt FIFO).
    const float la = logit_alpha[(cc << 6) + lane];
    const float d  = delta[0];
    const float* __restrict__ xb = x + (size_t)b * TT * CC + (cc << 6);
    float*       __restrict__ yb = y + (size_t)b * TT * CC + (cc << 6);
    float yv = xb[lane];             // y[-1] := x[0]; step 0 -> y0 = x0 exact

    float a = 1.0f / (1.0f + expf(-la));
    a = fminf(fmaxf(a, 1e-4f), 1.0f - 1e-4f);
    const float oma = 1.0f - a;

    // packed mapping: instr g covers t rows g*4..g*4+3; lane -> row lane>>4,
    // channels (lane&15)*4..+3  (per-lane global addr; LDS dst linear)
    const float* __restrict__ xl = xb + (size_t)(lane >> 4) * CC + ((lane & 15) << 2);
    float*       __restrict__ yl = yb + (size_t)(lane >> 4) * CC + ((lane & 15) << 2);

    // prologue: DMA tiles 0..3 into the ring (32 ops in flight)
    #pragma unroll
    for (int t = 0; t < RING; ++t) {
        #pragma unroll
        for (int g = 0; g < LPT; ++g)
            async16(xl + (size_t)(t * TILE + g * 4) * CC, &xs[t][g * 256]);
    }

    // head: exact FIFO wait counts while store stream ramps up
    tile_body<24, true >(0, xl, yl, xs[0], ys, yv, oma, d, lane);
    tile_body<32, true >(1, xl, yl, xs[1], ys, yv, oma, d, lane);
    tile_body<40, true >(2, xl, yl, xs[2], ys, yv, oma, d, lane);

    // steady state: vmcnt(48) = 3 trailing tiles x (8 st + 8 ld)
    for (int k = 3; k <= NTIL - 5; ++k)
        tile_body<48, true >(k, xl, yl, xs[k & 3], ys, yv, oma, d, lane);

    // tail: no more prefetch; counts shrink as the load FIFO empties
    tile_body<48, false>(NTIL - 4, xl, yl, xs[(NTIL - 4) & 3], ys, yv, oma, d, lane);
    tile_body<40, false>(NTIL - 3, xl, yl, xs[(NTIL - 3) & 3], ys, yv, oma, d, lane);
    tile_body<32, false>(NTIL - 2, xl, yl, xs[(NTIL - 2) & 3], ys, yv, oma, d, lane);
    tile_body<24, false>(NTIL - 1, xl, yl, xs[(NTIL - 1) & 3], ys, yv, oma, d, lane);
}

extern "C" void kernel_launch(void* const* d_in, const int* in_sizes, int n_in,
                              void* d_out, int out_size, void* d_ws, size_t ws_size,
                              hipStream_t stream) {
    const float* x  = (const float*)d_in[0];
    const float* la = (const float*)d_in[1];
    const float* dl = (const float*)d_in[2];
    float* y = (float*)d_out;

    huber_ema_kernel<<<dim3(256), dim3(64), 0, stream>>>(x, la, dl, y);
}

// Round 9
// 246.448 us; speedup vs baseline: 1.1008x; 1.1008x over previous
//
#include <hip/hip_runtime.h>
#include <math.h>

// HuberEMA: y[t] = y[t-1] + (1-a[c]) * clamp(x[t]-y[t-1], -d, +d); y[0] = x[0]
// B=32, T=2048, C=512 fp32. 16384 chains -> 256 blocks, 64 chains/block.
// Roofline: 268 MB => ~43 us @ 6.3 TB/s (1 MB per CU at 10.25 B/cyc share).
//
// R4/R5/R6 post-mortem: three different single-wave schedules all ~110 us
// (~130 cyc/timestep). Revised diagnosis: loads AND stores share the single
// wave's in-order vmcnt FIFO, so every load-wait also drains older (slow)
// HBM store-acks; plus no TLP at 1 wave/CU to hide it. Fix: producer/
// consumer WAVE SPECIALIZATION (3 waves/block, disjoint roles & FIFOs):
//   w0 producer: global_load_lds DMA into 4-slot ring, counted vmcnt only
//                (FIFO holds ONLY x loads; never reads LDS -> no hazards)
//   w1 consumer: ZERO loop VMEM - ds_read xin, serial chain, ds_write y
//   w2 storer:   ds_read y tile -> 8 coalesced dwordx4 global stores
//                (store-acks live only here and are never waited on)
// Sync: raw s_barrier (NOT __syncthreads - that drains vmcnt(0) and would
// kill the producer pipeline), sched_barrier(0) fences per rule #18.
// Producer issues tile k+3 in period k: slot (k+3)&3 != k&3 (race-free),
// 3-period lookahead (~3000+ cyc) >> 900-cyc HBM latency, 16-24 KB in
// flight per CU >= 9.2 KB Little's-law requirement.

#define TT   2048
#define CC   512
#define TILE 32
#define NTIL (TT / TILE)   // 64 tiles
#define LPT  8             // 1 KB global_load_lds ops per tile (8 KB tile)
#define RING 4

__device__ __forceinline__ void async16(const float* g, float* l) {
    // 64 lanes x 16 B: per-lane global src, wave-uniform LDS dst (+lane*16)
    __builtin_amdgcn_global_load_lds(
        (const __attribute__((address_space(1))) void*)g,
        (__attribute__((address_space(3))) void*)l, 16, 0, 0);
}

template<int N> __device__ __forceinline__ void vm_wait() {
    if constexpr (N == 0)  asm volatile("s_waitcnt vmcnt(0)"  ::: "memory");
    else if constexpr (N == 8)  asm volatile("s_waitcnt vmcnt(8)"  ::: "memory");
    else if constexpr (N == 16) asm volatile("s_waitcnt vmcnt(16)" ::: "memory");
    __builtin_amdgcn_sched_barrier(0);
}

__device__ __forceinline__ void lgkm0() {
    asm volatile("s_waitcnt lgkmcnt(0)" ::: "memory");
    __builtin_amdgcn_sched_barrier(0);
}

__device__ __forceinline__ void bar() {
    __builtin_amdgcn_sched_barrier(0);
    __builtin_amdgcn_s_barrier();
    __builtin_amdgcn_sched_barrier(0);
}

__global__ __launch_bounds__(192, 1)
void huber_ema_kernel(const float* __restrict__ x,
                      const float* __restrict__ logit_alpha,
                      const float* __restrict__ delta,
                      float* __restrict__ y)
{
    const int blk  = blockIdx.x;     // 0..255
    const int b    = blk >> 3;       // batch
    const int cc   = blk & 7;        // 64-wide channel chunk
    const int tid  = threadIdx.x;
    const int lane = tid & 63;
    const int wid  = tid >> 6;       // 0=producer 1=consumer 2=storer

    __shared__ float xs[RING][TILE * 64];   // 4 x 8 KB x ring
    __shared__ float ys[2][TILE * 64];      // 2 x 8 KB y double buffer

    const float* __restrict__ xb = x + (size_t)b * TT * CC + (cc << 6);
    float*       __restrict__ yb = y + (size_t)b * TT * CC + (cc << 6);
    // packed mapping (validated R6, absmax=0): instr g covers t rows
    // g*4..g*4+3; lane -> row lane>>4, channels (lane&15)*4..+3
    const float* __restrict__ xl = xb + (size_t)(lane >> 4) * CC + ((lane & 15) << 2);
    float*       __restrict__ yl = yb + (size_t)(lane >> 4) * CC + ((lane & 15) << 2);

    // consumer-only state
    float yv = 0.f, oma = 0.f, d = 0.f;

    if (wid == 0) {
        // prologue: DMA tiles 0,1,2 (24 ops); wait tile 0 landed (24->16)
        #pragma unroll
        for (int t = 0; t < 3; ++t) {
            #pragma unroll
            for (int g = 0; g < LPT; ++g)
                async16(xl + (size_t)(t * TILE + g * 4) * CC, &xs[t][g * 256]);
        }
        vm_wait<16>();
    } else if (wid == 1) {
        const float la = logit_alpha[(cc << 6) + lane];
        d  = delta[0];
        yv = xb[lane];               // y[-1] := x[0]; step 0 -> y0 = x0 exact
        float a = 1.0f / (1.0f + expf(-la));
        a = fminf(fmaxf(a, 1e-4f), 1.0f - 1e-4f);
        oma = 1.0f - a;
    }
    bar();   // B0: tile 0 in LDS

    for (int k = 0; k < NTIL; ++k) {
        if (wid == 0) {
            // issue tile k+3 into slot (k+3)&3 (consumer is on k&3);
            // then exact counted wait so tile k+1 is in LDS by the barrier
            if (k + 3 < NTIL) {
                #pragma unroll
                for (int g = 0; g < LPT; ++g)
                    async16(xl + (size_t)((k + 3) * TILE + g * 4) * CC,
                            &xs[(k + 3) & (RING - 1)][g * 256]);
                vm_wait<16>();          // outstanding k+1,k+2,k+3 -> k+1 done
            } else if (k == NTIL - 3) { vm_wait<8>(); }   // 62,63 -> 62 done
            else if (k == NTIL - 2)   { vm_wait<0>(); }   // 63 done
            // k == NTIL-1: nothing
        } else if (wid == 1) {
            const float* __restrict__ bx = xs[k & (RING - 1)];
            float*       __restrict__ by = ys[k & 1];
            float xin[TILE];
            #pragma unroll
            for (int i = 0; i < TILE; ++i) xin[i] = bx[i * 64 + lane];
            __builtin_amdgcn_sched_barrier(0);
            #pragma unroll
            for (int i = 0; i < TILE; ++i) {
                float r = xin[i] - yv;
                yv += oma * fminf(fmaxf(r, -d), d);
                by[i * 64 + lane] = yv;
            }
            lgkm0();                    // y writes visible before barrier
        } else {
            if (k > 0) {                // store tile k-1 from ys[(k-1)&1]
                const float* __restrict__ sy = ys[(k - 1) & 1];
                const size_t tb = (size_t)(k - 1) * TILE;
                #pragma unroll
                for (int g = 0; g < LPT; ++g) {
                    float4 v = *(const float4*)&sy[g * 256 + (lane << 2)];
                    *(float4*)(yl + (tb + (size_t)(g * 4)) * CC) = v;
                }
            }
        }
        bar();
    }

    // epilogue: storer writes the final tile (consumer's lgkm0 + last bar
    // made it visible); other waves simply exit
    if (wid == 2) {
        const float* __restrict__ sy = ys[(NTIL - 1) & 1];
        const size_t tb = (size_t)(NTIL - 1) * TILE;
        #pragma unroll
        for (int g = 0; g < LPT; ++g) {
            float4 v = *(const float4*)&sy[g * 256 + (lane << 2)];
            *(float4*)(yl + (tb + (size_t)(g * 4)) * CC) = v;
        }
    }
}

extern "C" void kernel_launch(void* const* d_in, const int* in_sizes, int n_in,
                              void* d_out, int out_size, void* d_ws, size_t ws_size,
                              hipStream_t stream) {
    const float* x  = (const float*)d_in[0];
    const float* la = (const float*)d_in[1];
    const float* dl = (const float*)d_in[2];
    float* y = (float*)d_out;

    huber_ema_kernel<<<dim3(256), dim3(192), 0, stream>>>(x, la, dl, y);
}